// Round 7
// baseline (4746.814 us; speedup 1.0000x reference)
//
#include <hip/hip_runtime.h>

#define BSZ 32
#define NN 24
#define TT 12
#define FF 3
#define KK 3
#define COUT 12
#define DIN 313          // N*COUT + N + 1
#define HID 3756         // DIN*T
#define H4 15024         // 4*HID
#define KP 3776          // HID padded to 118*32
#define KPI 320          // DIN padded to 10*32
#define NTILES 470       // ceil(15024/32)
#define LGRID 512        // persistent LSTM grid (2 blocks/CU guaranteed resident)

using short8 = __attribute__((ext_vector_type(8))) short;
using f32x4  = __attribute__((ext_vector_type(4))) float;

__device__ inline unsigned short f2bf(float f){
  union{float f; unsigned u;} v; v.f=f;
  unsigned u=v.u;
  return (unsigned short)((u + 0x7FFFu + ((u>>16)&1u))>>16);
}
__device__ inline f32x4 mfma16(short8 a, short8 b, f32x4 c){
  return __builtin_amdgcn_mfma_f32_16x16x32_bf16(a,b,c,0,0,0);
}
__device__ inline float sigm(float x){ return 1.f/(1.f+expf(-x)); }

// ---------- fp32 -> bf16 conversion with K padding ----------
__global__ void k_conv(const float* __restrict__ in, unsigned short* __restrict__ out,
                       int rows, int kin, int kout){
  int g4 = kout>>2;
  long total = (long)rows*g4;
  bool vec = (kin&3)==0;
  for(long i=(long)blockIdx.x*blockDim.x+threadIdx.x; i<total; i+=(long)gridDim.x*blockDim.x){
    int g=(int)(i%g4); int r=(int)(i/g4);
    int k=g*4;
    ushort4 o;
    if(vec && k+3<kin){
      float4 v = *(const float4*)(in + (long)r*kin + k);
      o.x=f2bf(v.x); o.y=f2bf(v.y); o.z=f2bf(v.z); o.w=f2bf(v.w);
    } else {
      float vv[4];
      #pragma unroll
      for(int q=0;q<4;q++){ int kk=k+q; vv[q]=(kk<kin)? in[(long)r*kin+kk] : 0.f; }
      o.x=f2bf(vv[0]); o.y=f2bf(vv[1]); o.z=f2bf(vv[2]); o.w=f2bf(vv[3]);
    }
    *(ushort4*)(out + (long)r*kout + k) = o;
  }
}

// ---------- zero the grid-barrier counter (graph-replay safe) ----------
__global__ void k_zero(unsigned int* bar){ if(threadIdx.x==0) *bar=0u; }

// ---------- spatial + temporal attention (pre batch-softmax), per batch ----------
__global__ void k_attn(const float* __restrict__ X, const float* __restrict__ sa_W1,
   const float* __restrict__ sa_W2, const float* __restrict__ sa_W3,
   const float* __restrict__ sa_bs, const float* __restrict__ sa_Vs,
   const float* __restrict__ ta_U1, const float* __restrict__ ta_U2,
   const float* __restrict__ ta_U3, const float* __restrict__ ta_be,
   const float* __restrict__ ta_Ve,
   float* __restrict__ SA_pre, float* __restrict__ TA_pre){
  int b=blockIdx.x, tid=threadIdx.x;
  __shared__ float lin[864];            // raw X[b], layout [n][t][f]
  __shared__ float lhs[NN*TT];
  __shared__ float rhs[TT*NN];
  __shared__ float P[NN*NN];
  __shared__ float S[NN*NN];
  __shared__ float lhsT[TT*NN];
  __shared__ float rhsT[NN*TT];
  __shared__ float PT[TT*TT];
  __shared__ float E[TT*TT];
  for(int i=tid;i<864;i+=256) lin[i]=X[b*864+i];
  __syncthreads();
  for(int i=tid;i<NN*TT;i+=256){ int n=i/TT, t=i%TT;
    float acc=0;
    #pragma unroll
    for(int f=0;f<FF;f++){
      float t1=0;
      for(int u=0;u<TT;u++) t1 += lin[n*36+u*3+f]*sa_W1[u];
      acc += t1*sa_W2[f*TT+t];
    }
    lhs[n*TT+t]=acc;
    float r=0;
    #pragma unroll
    for(int f=0;f<FF;f++) r += sa_W3[f]*lin[n*36+t*3+f];
    rhs[t*NN+n]=r;
  }
  for(int i=tid;i<TT*NN;i+=256){ int t=i/NN, n=i%NN;
    float acc=0;
    #pragma unroll
    for(int f=0;f<FF;f++){
      float t1=0;
      for(int m=0;m<NN;m++) t1 += lin[m*36+t*3+f]*ta_U1[m];
      acc += t1*ta_U2[f*NN+n];
    }
    lhsT[t*NN+n]=acc;
    float r=0;
    #pragma unroll
    for(int f=0;f<FF;f++) r += ta_U3[f]*lin[n*36+t*3+f];
    rhsT[n*TT+t]=r;
  }
  __syncthreads();
  for(int i=tid;i<NN*NN;i+=256){ int n=i/NN,m=i%NN;
    float a=0;
    for(int t=0;t<TT;t++) a+=lhs[n*TT+t]*rhs[t*NN+m];
    P[i]=sigm(a+sa_bs[i]);
  }
  for(int i=tid;i<TT*TT;i+=256){ int t=i/TT,u=i%TT;
    float a=0;
    for(int n=0;n<NN;n++) a+=lhsT[t*NN+n]*rhsT[n*TT+u];
    PT[i]=sigm(a+ta_be[i]);
  }
  __syncthreads();
  for(int i=tid;i<NN*NN;i+=256){ int n=i/NN,k=i%NN;
    float a=0;
    for(int m=0;m<NN;m++) a+=sa_Vs[n*NN+m]*P[m*NN+k];
    S[i]=a;
  }
  for(int i=tid;i<TT*TT;i+=256){ int t=i/TT,v=i%TT;
    float a=0;
    for(int u=0;u<TT;u++) a+=ta_Ve[t*TT+u]*PT[u*TT+v];
    E[i]=a;
  }
  __syncthreads();
  if(tid<NN){ int k=tid;
    float mx=-1e30f;
    for(int n=0;n<NN;n++) mx=fmaxf(mx,S[n*NN+k]);
    float sm=0;
    for(int n=0;n<NN;n++) sm+=__expf(S[n*NN+k]-mx);
    for(int n=0;n<NN;n++){
      float v=__expf(S[n*NN+k]-mx)/sm;
      SA_pre[b*576+n*NN+k]=sigm(v);
    }
  }
  if(tid>=32 && tid<32+TT){ int v=tid-32;
    float mx=-1e30f;
    for(int t=0;t<TT;t++) mx=fmaxf(mx,E[t*TT+v]);
    float sm=0;
    for(int t=0;t<TT;t++) sm+=__expf(E[t*TT+v]-mx);
    for(int t=0;t<TT;t++){
      float e=__expf(E[t*TT+v]-mx)/sm;
      TA_pre[b*144+t*TT+v]=sigm(e);
    }
  }
}

// ---------- softmax over batch axis; s_a also written to OUTPUT as float ----------
__global__ void k_bsoftmax(const float* __restrict__ SA_pre, const float* __restrict__ TA_pre,
    float* __restrict__ s_a, float* __restrict__ t_a, float* __restrict__ out_sa){
  int i=blockIdx.x*blockDim.x+threadIdx.x;
  if(i<576){
    float mx=-1e30f;
    for(int b=0;b<BSZ;b++) mx=fmaxf(mx,SA_pre[b*576+i]);
    float sm=0;
    for(int b=0;b<BSZ;b++) sm+=__expf(SA_pre[b*576+i]-mx);
    for(int b=0;b<BSZ;b++){
      float v=__expf(SA_pre[b*576+i]-mx)/sm;
      s_a[b*576+i]=v;
      out_sa[b*576+i]=v;
    }
  } else if(i<720){
    int j=i-576;
    float mx=-1e30f;
    for(int b=0;b<BSZ;b++) mx=fmaxf(mx,TA_pre[b*144+j]);
    float sm=0;
    for(int b=0;b<BSZ;b++) sm+=__expf(TA_pre[b*144+j]-mx);
    for(int b=0;b<BSZ;b++) t_a[b*144+j]=__expf(TA_pre[b*144+j]-mx)/sm;
  }
}

// ---------- graph conv + LN + temporal mix + input layer, per batch ----------
__global__ void k_graph(const float* __restrict__ X, const float* __restrict__ cheb,
  const float* __restrict__ s_a, const float* __restrict__ t_a,
  const float* __restrict__ theta, const float* __restrict__ cheb_bias,
  const float* __restrict__ ln_g, const float* __restrict__ ln_b,
  const float* __restrict__ liw, const float* __restrict__ lib,
  float* __restrict__ x_in){
  int b=blockIdx.x, tid=threadIdx.x;
  __shared__ float lin[864];
  __shared__ float A2[KK*NN*NN];
  __shared__ float rg[KK*NN*FF*TT];
  __shared__ float xc[NN*COUT*TT];
  __shared__ float xres[DIN*TT];
  __shared__ float ta_s[TT*TT];
  for(int i=tid;i<864;i+=320) lin[i]=X[b*864+i];
  for(int i=tid;i<KK*NN*NN;i+=320){ int mn=i%576; A2[i]=cheb[i]*s_a[b*576+mn]; }
  for(int i=tid;i<144;i+=320) ta_s[i]=t_a[b*144+i];
  __syncthreads();
  for(int i=tid;i<KK*NN*FF*TT;i+=320){
    int t=i%TT, f=(i/TT)%FF, n=(i/36)%NN, k=i/864;
    float a=0;
    for(int m=0;m<NN;m++) a+=A2[k*576+m*NN+n]*lin[m*36+f*TT+t];
    rg[i]=a;
  }
  __syncthreads();
  for(int i=tid;i<NN*COUT*TT;i+=320){
    int t=i%TT, o=(i/TT)%COUT, n=i/(COUT*TT);
    float a=cheb_bias[o];
    #pragma unroll
    for(int k=0;k<KK;k++)
      #pragma unroll
      for(int f=0;f<FF;f++)
        a += rg[((k*NN+n)*FF+f)*TT+t]*theta[(k*FF+f)*COUT+o];
    xc[i]=fmaxf(a,0.f);
  }
  __syncthreads();
  if(tid<NN*COUT){
    float mu=0;
    for(int t=0;t<TT;t++) mu+=xc[tid*TT+t];
    mu*=(1.f/12.f);
    float var=0;
    for(int t=0;t<TT;t++){ float d=xc[tid*TT+t]-mu; var+=d*d; }
    var*=(1.f/12.f);
    float inv=rsqrtf(var+1e-5f);
    for(int t=0;t<TT;t++) xc[tid*TT+t]=(xc[tid*TT+t]-mu)*inv*ln_g[t]+ln_b[t];
  }
  __syncthreads();
  for(int i=tid;i<NN*COUT;i+=320){
    for(int v=0;v<TT;v++){
      float a=0;
      for(int t=0;t<TT;t++) a+=xc[i*TT+t]*ta_s[t*TT+v];
      xres[i*TT+v]=a;
    }
  }
  for(int i=tid;i<25*TT;i+=320){
    int r=i/TT, t=i%TT;
    float v=(r<NN)? lin[r*36+t*3+0] : lin[t*3+1];
    xres[(288+r)*TT+t]=v;
  }
  __syncthreads();
  for(int i=tid;i<DIN;i+=320){
    for(int t=0;t<TT;t++){
      float a=lib[t];
      #pragma unroll
      for(int u=0;u<TT;u++) a+=xres[i*TT+u]*liw[t*TT+u];
      x_in[((long)b*DIN+i)*TT+t]=a;
    }
  }
}

// ---------- per-(t,b): alpha softmax gate, xi -> bf16 padded [t*32+b][KPI] ----------
__global__ void __launch_bounds__(512) k_alpha(const float* __restrict__ x_in,
    const float* __restrict__ sa2_w, const float* __restrict__ sa2_b,
    unsigned short* __restrict__ xi_b){
  int blk=blockIdx.x; int t=blk>>5, b=blk&31; int tid=threadIdx.x;
  __shared__ float xt[DIN];
  __shared__ float red[512];
  if(tid<DIN) xt[tid]=x_in[((long)b*DIN+tid)*TT+t];
  __syncthreads();
  float z=-1e30f, e=0.f;
  if(tid<DIN){
    float a=sa2_b[tid];
    const float* wr=sa2_w+(long)tid*DIN;
    for(int i=0;i<DIN;i++) a+=xt[i]*wr[i];
    z=sigm(a);
  }
  red[tid]=z; __syncthreads();
  for(int off=256;off>0;off>>=1){ if(tid<off) red[tid]=fmaxf(red[tid],red[tid+off]); __syncthreads(); }
  float mx=red[0]; __syncthreads();
  e=(tid<DIN)?__expf(z-mx):0.f;
  red[tid]=e; __syncthreads();
  for(int off=256;off>0;off>>=1){ if(tid<off) red[tid]+=red[tid+off]; __syncthreads(); }
  float sm=red[0];
  if(tid<KPI){
    unsigned short v=0;
    if(tid<DIN){
      float alpha=e/sm;
      v=f2bf(xt[tid]*alpha+xt[tid]);
    }
    xi_b[(long)blk*KPI+tid]=v;
  }
}

// ---------- Gx[t][b][j] = xi @ W_ih^T + b_ih + b_hh (bf16 MFMA; W_ih fp32 read+cvt in regs) ----------
__global__ void __launch_bounds__(256) k_gx(const unsigned short* __restrict__ xi,
   const float* __restrict__ Wih, const float* __restrict__ b_ih,
   const float* __restrict__ b_hh, float* __restrict__ Gx){
  int w=threadIdx.x>>6, lane=threadIdx.x&63;
  int jt=blockIdx.x*4+w;
  if(jt>=NTILES) return;
  int j0=jt*32;
  int lj=lane&15, lk=lane>>4;
  short8 bfr[10][2];
  #pragma unroll
  for(int ks=0;ks<10;ks++)
    #pragma unroll
    for(int jh=0;jh<2;jh++){
      int j=j0+jh*16+lj;
      short8 bv;
      #pragma unroll
      for(int q=0;q<8;q++){
        int k=ks*32+lk*8+q;
        float f=(j<H4 && k<DIN)? Wih[(long)j*DIN+k] : 0.f;
        bv[q]=(short)f2bf(f);
      }
      bfr[ks][jh]=bv;
    }
  for(int t=0;t<TT;t++){
    f32x4 acc[2][2]={};
    #pragma unroll
    for(int ks=0;ks<10;ks++){
      #pragma unroll
      for(int mh=0;mh<2;mh++){
        short8 a=*(const short8*)(xi + ((long)(t*32+mh*16+lj))*KPI + ks*32 + lk*8);
        acc[mh][0]=mfma16(a,bfr[ks][0],acc[mh][0]);
        acc[mh][1]=mfma16(a,bfr[ks][1],acc[mh][1]);
      }
    }
    #pragma unroll
    for(int mh=0;mh<2;mh++)
      #pragma unroll
      for(int jh=0;jh<2;jh++){
        int j=j0+jh*16+lj;
        if(j<H4){
          float bias=b_ih[j]+b_hh[j];
          #pragma unroll
          for(int r=0;r<4;r++){
            int bb=mh*16+lk*4+r;     // C/D: col=lane&15, row=(lane>>4)*4+r  (m89-verified)
            Gx[((long)t*32+bb)*H4+j]=acc[mh][jh][r]+bias;
          }
        }
      }
  }
}

// ---------- device-scope grid barrier (co-resident grid; G16 pattern) ----------
__device__ inline void gridbar(unsigned int* bar, unsigned int tgt){
  __threadfence();                 // release: my writes visible device-wide
  __syncthreads();
  if(threadIdx.x==0){
    atomicAdd(bar,1u);
    while(atomicAdd(bar,0u)<tgt) __builtin_amdgcn_s_sleep(2);
  }
  __syncthreads();
  __threadfence();                 // acquire: don't read stale cache lines
}

// ---------- persistent 12-step LSTM: MFMA phase + update phase per step ----------
__global__ void __launch_bounds__(512,4) k_lstm(
    unsigned short* __restrict__ h_b, const unsigned short* __restrict__ Whh,
    const float* __restrict__ Gx, const float* __restrict__ c0,
    float* __restrict__ c, float* __restrict__ hs, float* __restrict__ gates,
    unsigned int* __restrict__ bar){
  const int tid=threadIdx.x;
  const int w=tid>>6, lane=tid&63;
  const int bi=blockIdx.x;
  const int j0=bi*32;
  const int lj=lane&15, lk=lane>>4;
  const int s0=(118*w)>>3, s1=(118*(w+1))>>3;   // 8-way K split, 14-15 steps each
  const short8 z8={0,0,0,0,0,0,0,0};
  __shared__ float red[8][1024];
  const bool jvalid = j0 < H4;
  const bool jok1 = (j0+16+lj) < H4;
  const int g = bi*512+tid;                      // update-phase element
  const bool uok = g < BSZ*HID;
  const int ub = g/HID, uj = g-ub*HID;
  unsigned int bcount=0;
  for(int t=0;t<TT;t++){
    if(jvalid){
      f32x4 acc[2][2]={};
      for(int ks=s0;ks<s1;ks++){
        int kofs=ks*32+lk*8;
        short8 b0=*(const short8*)(Whh+(long)(j0+lj)*KP+kofs);
        short8 b1=jok1?*(const short8*)(Whh+(long)(j0+16+lj)*KP+kofs):z8;
        short8 a0=*(const short8*)(h_b+(long)lj*KP+kofs);
        short8 a1=*(const short8*)(h_b+(long)(16+lj)*KP+kofs);
        acc[0][0]=mfma16(a0,b0,acc[0][0]);
        acc[0][1]=mfma16(a0,b1,acc[0][1]);
        acc[1][0]=mfma16(a1,b0,acc[1][0]);
        acc[1][1]=mfma16(a1,b1,acc[1][1]);
      }
      #pragma unroll
      for(int mh=0;mh<2;mh++)
        #pragma unroll
        for(int jh=0;jh<2;jh++)
          #pragma unroll
          for(int r=0;r<4;r++)
            red[w][(mh*16+lk*4+r)*32+jh*16+lj]=acc[mh][jh][r];
    }
    __syncthreads();
    if(jvalid){
      for(int p=tid;p<1024;p+=512){
        int bb=p>>5, jl=p&31; int j=j0+jl;
        if(j<H4){
          float s=red[0][p]+red[1][p]+red[2][p]+red[3][p]
                 +red[4][p]+red[5][p]+red[6][p]+red[7][p];
          gates[(long)bb*H4+j]=s+Gx[((long)t*BSZ+bb)*H4+j];
        }
      }
    }
    gridbar(bar,(++bcount)*LGRID);               // gates ready
    if(uok){
      long o=(long)ub*H4;
      float gi=sigm(gates[o+uj]);
      float gf=sigm(gates[o+uj+HID]);
      float gg=tanhf(gates[o+uj+2*HID]);
      float go=sigm(gates[o+uj+3*HID]);
      float cin=(t==0)?c0[g]:c[g];
      float c2=gf*cin+gi*gg;
      float h2=go*tanhf(c2);
      c[g]=c2;
      hs[(long)t*BSZ*HID+g]=h2;
      h_b[(long)ub*KP+uj]=f2bf(h2);
    }
    gridbar(bar,(++bcount)*LGRID);               // h ready for next step
  }
}

// ---------- beta = softmax(relu(total_ht @ ta2_w^T + ta2_b)) ----------
__global__ void k_beta(const float* __restrict__ hs, const float* __restrict__ ta2_w,
    const float* __restrict__ ta2_b, float* __restrict__ beta){
  int b=blockIdx.x, tid=threadIdx.x;
  float p[12]={0,0,0,0,0,0,0,0,0,0,0,0};
  for(int idx=tid; idx<TT*HID; idx+=256){
    int t=idx/HID, j=idx%HID;
    float v=hs[((long)t*BSZ+b)*HID+j];
    #pragma unroll
    for(int q=0;q<12;q++) p[q]+=v*ta2_w[(long)q*TT*HID+idx];
  }
  __shared__ float red[256];
  float z[12];
  #pragma unroll
  for(int q=0;q<12;q++){
    __syncthreads();
    red[tid]=p[q]; __syncthreads();
    for(int off=128;off>0;off>>=1){ if(tid<off) red[tid]+=red[tid+off]; __syncthreads(); }
    z[q]=red[0];
  }
  if(tid==0){
    float mx=-1e30f;
    #pragma unroll
    for(int q=0;q<12;q++){ z[q]=fmaxf(z[q]+ta2_b[q],0.f); mx=fmaxf(mx,z[q]); }
    float sm=0;
    #pragma unroll
    for(int q=0;q<12;q++){ z[q]=__expf(z[q]-mx); sm+=z[q]; }
    #pragma unroll
    for(int q=0;q<12;q++) beta[b*12+q]=z[q]/sm;
  }
}

// ---------- final output (float) ----------
__global__ void k_out(const float* __restrict__ hs, const float* __restrict__ beta,
   const float* __restrict__ x_in, const float* __restrict__ out_w,
   const float* __restrict__ out_b, float* __restrict__ out0){
  int b=blockIdx.x, tid=threadIdx.x;
  float bt[12];
  #pragma unroll
  for(int q=0;q<12;q++) bt[q]=beta[b*12+q];
  float acc=0;
  for(int j=tid;j<HID;j+=256){
    float ov=0;
    #pragma unroll
    for(int t=0;t<TT;t++) ov+=hs[((long)t*BSZ+b)*HID+j]*bt[t];
    ov+=x_in[(long)b*HID+j];
    acc+=fmaxf(ov,0.f)*out_w[j];
  }
  __shared__ float red[256];
  red[tid]=acc; __syncthreads();
  for(int off=128;off>0;off>>=1){ if(tid<off) red[tid]+=red[tid+off]; __syncthreads(); }
  if(tid==0) out0[b]=red[0]+out_b[0];
}

extern "C" void kernel_launch(void* const* d_in, const int* in_sizes, int n_in,
                              void* d_out, int out_size, void* d_ws, size_t ws_size,
                              hipStream_t stream){
  (void)in_sizes; (void)n_in; (void)out_size; (void)ws_size;
  const float* X     =(const float*)d_in[0];
  const float* cheb  =(const float*)d_in[1];
  const float* sa_W1 =(const float*)d_in[2];
  const float* sa_W2 =(const float*)d_in[3];
  const float* sa_W3 =(const float*)d_in[4];
  const float* sa_bs =(const float*)d_in[5];
  const float* sa_Vs =(const float*)d_in[6];
  const float* ta_U1 =(const float*)d_in[7];
  const float* ta_U2 =(const float*)d_in[8];
  const float* ta_U3 =(const float*)d_in[9];
  const float* ta_be =(const float*)d_in[10];
  const float* ta_Ve =(const float*)d_in[11];
  const float* theta =(const float*)d_in[12];
  const float* cb    =(const float*)d_in[13];
  const float* ln_g  =(const float*)d_in[14];
  const float* ln_b  =(const float*)d_in[15];
  const float* liw   =(const float*)d_in[16];
  const float* lib   =(const float*)d_in[17];
  const float* sa2_w =(const float*)d_in[18];
  const float* sa2_b =(const float*)d_in[19];
  const float* W_ih  =(const float*)d_in[20];
  const float* W_hh  =(const float*)d_in[21];
  const float* b_ih  =(const float*)d_in[22];
  const float* b_hh  =(const float*)d_in[23];
  const float* ta2_w =(const float*)d_in[24];
  const float* ta2_b =(const float*)d_in[25];
  const float* out_w =(const float*)d_in[26];
  const float* out_b =(const float*)d_in[27];
  const float* h0    =(const float*)d_in[28];
  const float* c0    =(const float*)d_in[29];

  char* w=(char*)d_ws;
  unsigned short* Whh_b=(unsigned short*)(w);                 // 113,461,248
  float* Gx   =(float*)(w+123076608);                         // 23,076,864
  float* gates=(float*)(w+146153472);                         //  1,923,072
  float* hs   =(float*)(w+149999616);                         //  5,769,216
  unsigned short* h_b=(unsigned short*)(w+155768832);         //    241,664
  float* c    =(float*)(w+156010496);                         //    480,768
  float* x_in =(float*)(w+156491264);                         //    480,768
  unsigned short* xi_b=(unsigned short*)(w+156972032);        //    245,760
  float* SA   =(float*)(w+157217792);
  float* TA   =(float*)(w+157291520);
  float* s_a  =(float*)(w+157309952);
  float* t_a  =(float*)(w+157383680);
  float* beta =(float*)(w+157402112);
  unsigned int* bar=(unsigned int*)(w+157405184);
  float* out_f=(float*)d_out;                                 // [0..31]=out, [32..]=s_a

  k_zero<<<1,64,0,stream>>>(bar);
  k_conv<<<2048,256,0,stream>>>(W_hh, Whh_b, H4, HID, KP);
  k_conv<<<118,256,0,stream>>>(h0, h_b, BSZ, HID, KP);
  k_attn<<<32,256,0,stream>>>(X,sa_W1,sa_W2,sa_W3,sa_bs,sa_Vs,ta_U1,ta_U2,ta_U3,ta_be,ta_Ve,SA,TA);
  k_bsoftmax<<<3,256,0,stream>>>(SA,TA,s_a,t_a,out_f+32);
  k_graph<<<32,320,0,stream>>>(X,cheb,s_a,t_a,theta,cb,ln_g,ln_b,liw,lib,x_in);
  k_alpha<<<384,512,0,stream>>>(x_in,sa2_w,sa2_b,xi_b);
  k_gx<<<118,256,0,stream>>>(xi_b,W_ih,b_ih,b_hh,Gx);
  k_lstm<<<LGRID,512,0,stream>>>(h_b,Whh_b,Gx,c0,c,hs,gates,bar);
  k_beta<<<32,256,0,stream>>>(hs,ta2_w,ta2_b,beta);
  k_out<<<32,256,0,stream>>>(hs,beta,x_in,out_w,out_b,out_f);
}

// Round 8
// 633.185 us; speedup vs baseline: 7.4967x; 7.4967x over previous
//
#include <hip/hip_runtime.h>

#define BSZ 32
#define NN 24
#define TT 12
#define FF 3
#define KK 3
#define COUT 12
#define DIN 313          // N*COUT + N + 1
#define HID 3756         // DIN*T
#define H4 15024         // 4*HID
#define KP 3776          // HID padded to 118*32
#define KPI 320          // DIN padded to 10*32
#define NTILES 470       // ceil(15024/32)
#define NB 235           // ceil(3756/16) j-tiles for fused step

using short8 = __attribute__((ext_vector_type(8))) short;
using f32x4  = __attribute__((ext_vector_type(4))) float;

__device__ inline unsigned short f2bf(float f){
  union{float f; unsigned u;} v; v.f=f;
  unsigned u=v.u;
  return (unsigned short)((u + 0x7FFFu + ((u>>16)&1u))>>16);
}
__device__ inline f32x4 mfma16(short8 a, short8 b, f32x4 c){
  return __builtin_amdgcn_mfma_f32_16x16x32_bf16(a,b,c,0,0,0);
}
__device__ inline float sigm(float x){ return 1.f/(1.f+expf(-x)); }

// ---------- fused fp32->bf16 conversion: W_hh rows + h0 rows (dual-dest) ----------
__global__ void k_convall(const float* __restrict__ W, const float* __restrict__ h0f,
    unsigned short* __restrict__ Wb, unsigned short* __restrict__ hb0,
    unsigned short* __restrict__ hb1){
  const int g4 = KP>>2;                 // 944 groups of 4
  long total = (long)(H4+BSZ)*g4;
  for(long i=(long)blockIdx.x*blockDim.x+threadIdx.x; i<total; i+=(long)gridDim.x*blockDim.x){
    int g=(int)(i%g4); int r=(int)(i/g4);
    int k=g*4;
    const float* src; 
    bool isW = r<H4;
    src = isW ? (W + (long)r*HID) : (h0f + (long)(r-H4)*HID);
    ushort4 o;
    if(k+3<HID){
      float4 v=*(const float4*)(src+k);
      o.x=f2bf(v.x); o.y=f2bf(v.y); o.z=f2bf(v.z); o.w=f2bf(v.w);
    } else {
      float vv[4];
      #pragma unroll
      for(int q=0;q<4;q++){ int kk=k+q; vv[q]=(kk<HID)? src[kk] : 0.f; }
      o.x=f2bf(vv[0]); o.y=f2bf(vv[1]); o.z=f2bf(vv[2]); o.w=f2bf(vv[3]);
    }
    if(isW) *(ushort4*)(Wb + (long)r*KP + k) = o;
    else {
      *(ushort4*)(hb0 + (long)(r-H4)*KP + k) = o;
      *(ushort4*)(hb1 + (long)(r-H4)*KP + k) = o;   // init pad (and values) of pong buffer
    }
  }
}

// ---------- spatial + temporal attention (pre batch-softmax), per batch ----------
__global__ void k_attn(const float* __restrict__ X, const float* __restrict__ sa_W1,
   const float* __restrict__ sa_W2, const float* __restrict__ sa_W3,
   const float* __restrict__ sa_bs, const float* __restrict__ sa_Vs,
   const float* __restrict__ ta_U1, const float* __restrict__ ta_U2,
   const float* __restrict__ ta_U3, const float* __restrict__ ta_be,
   const float* __restrict__ ta_Ve,
   float* __restrict__ SA_pre, float* __restrict__ TA_pre){
  int b=blockIdx.x, tid=threadIdx.x;
  __shared__ float lin[864];            // raw X[b], layout [n][t][f]
  __shared__ float lhs[NN*TT];
  __shared__ float rhs[TT*NN];
  __shared__ float P[NN*NN];
  __shared__ float S[NN*NN];
  __shared__ float lhsT[TT*NN];
  __shared__ float rhsT[NN*TT];
  __shared__ float PT[TT*TT];
  __shared__ float E[TT*TT];
  for(int i=tid;i<864;i+=256) lin[i]=X[b*864+i];
  __syncthreads();
  for(int i=tid;i<NN*TT;i+=256){ int n=i/TT, t=i%TT;
    float acc=0;
    #pragma unroll
    for(int f=0;f<FF;f++){
      float t1=0;
      for(int u=0;u<TT;u++) t1 += lin[n*36+u*3+f]*sa_W1[u];
      acc += t1*sa_W2[f*TT+t];
    }
    lhs[n*TT+t]=acc;
    float r=0;
    #pragma unroll
    for(int f=0;f<FF;f++) r += sa_W3[f]*lin[n*36+t*3+f];
    rhs[t*NN+n]=r;
  }
  for(int i=tid;i<TT*NN;i+=256){ int t=i/NN, n=i%NN;
    float acc=0;
    #pragma unroll
    for(int f=0;f<FF;f++){
      float t1=0;
      for(int m=0;m<NN;m++) t1 += lin[m*36+t*3+f]*ta_U1[m];
      acc += t1*ta_U2[f*NN+n];
    }
    lhsT[t*NN+n]=acc;
    float r=0;
    #pragma unroll
    for(int f=0;f<FF;f++) r += ta_U3[f]*lin[n*36+t*3+f];
    rhsT[n*TT+t]=r;
  }
  __syncthreads();
  for(int i=tid;i<NN*NN;i+=256){ int n=i/NN,m=i%NN;
    float a=0;
    for(int t=0;t<TT;t++) a+=lhs[n*TT+t]*rhs[t*NN+m];
    P[i]=sigm(a+sa_bs[i]);
  }
  for(int i=tid;i<TT*TT;i+=256){ int t=i/TT,u=i%TT;
    float a=0;
    for(int n=0;n<NN;n++) a+=lhsT[t*NN+n]*rhsT[n*TT+u];
    PT[i]=sigm(a+ta_be[i]);
  }
  __syncthreads();
  for(int i=tid;i<NN*NN;i+=256){ int n=i/NN,k=i%NN;
    float a=0;
    for(int m=0;m<NN;m++) a+=sa_Vs[n*NN+m]*P[m*NN+k];
    S[i]=a;
  }
  for(int i=tid;i<TT*TT;i+=256){ int t=i/TT,v=i%TT;
    float a=0;
    for(int u=0;u<TT;u++) a+=ta_Ve[t*TT+u]*PT[u*TT+v];
    E[i]=a;
  }
  __syncthreads();
  if(tid<NN){ int k=tid;
    float mx=-1e30f;
    for(int n=0;n<NN;n++) mx=fmaxf(mx,S[n*NN+k]);
    float sm=0;
    for(int n=0;n<NN;n++) sm+=__expf(S[n*NN+k]-mx);
    for(int n=0;n<NN;n++){
      float v=__expf(S[n*NN+k]-mx)/sm;
      SA_pre[b*576+n*NN+k]=sigm(v);
    }
  }
  if(tid>=32 && tid<32+TT){ int v=tid-32;
    float mx=-1e30f;
    for(int t=0;t<TT;t++) mx=fmaxf(mx,E[t*TT+v]);
    float sm=0;
    for(int t=0;t<TT;t++) sm+=__expf(E[t*TT+v]-mx);
    for(int t=0;t<TT;t++){
      float e=__expf(E[t*TT+v]-mx)/sm;
      TA_pre[b*144+t*TT+v]=sigm(e);
    }
  }
}

// ---------- softmax over batch axis; s_a also written to OUTPUT as float ----------
__global__ void k_bsoftmax(const float* __restrict__ SA_pre, const float* __restrict__ TA_pre,
    float* __restrict__ s_a, float* __restrict__ t_a, float* __restrict__ out_sa){
  int i=blockIdx.x*blockDim.x+threadIdx.x;
  if(i<576){
    float mx=-1e30f;
    for(int b=0;b<BSZ;b++) mx=fmaxf(mx,SA_pre[b*576+i]);
    float sm=0;
    for(int b=0;b<BSZ;b++) sm+=__expf(SA_pre[b*576+i]-mx);
    for(int b=0;b<BSZ;b++){
      float v=__expf(SA_pre[b*576+i]-mx)/sm;
      s_a[b*576+i]=v;
      out_sa[b*576+i]=v;
    }
  } else if(i<720){
    int j=i-576;
    float mx=-1e30f;
    for(int b=0;b<BSZ;b++) mx=fmaxf(mx,TA_pre[b*144+j]);
    float sm=0;
    for(int b=0;b<BSZ;b++) sm+=__expf(TA_pre[b*144+j]-mx);
    for(int b=0;b<BSZ;b++) t_a[b*144+j]=__expf(TA_pre[b*144+j]-mx)/sm;
  }
}

// ---------- graph conv + LN + temporal mix + input layer, per batch ----------
__global__ void k_graph(const float* __restrict__ X, const float* __restrict__ cheb,
  const float* __restrict__ s_a, const float* __restrict__ t_a,
  const float* __restrict__ theta, const float* __restrict__ cheb_bias,
  const float* __restrict__ ln_g, const float* __restrict__ ln_b,
  const float* __restrict__ liw, const float* __restrict__ lib,
  float* __restrict__ x_in){
  int b=blockIdx.x, tid=threadIdx.x;
  __shared__ float lin[864];
  __shared__ float A2[KK*NN*NN];
  __shared__ float rg[KK*NN*FF*TT];
  __shared__ float xc[NN*COUT*TT];
  __shared__ float xres[DIN*TT];
  __shared__ float ta_s[TT*TT];
  for(int i=tid;i<864;i+=320) lin[i]=X[b*864+i];
  for(int i=tid;i<KK*NN*NN;i+=320){ int mn=i%576; A2[i]=cheb[i]*s_a[b*576+mn]; }
  for(int i=tid;i<144;i+=320) ta_s[i]=t_a[b*144+i];
  __syncthreads();
  for(int i=tid;i<KK*NN*FF*TT;i+=320){
    int t=i%TT, f=(i/TT)%FF, n=(i/36)%NN, k=i/864;
    float a=0;
    for(int m=0;m<NN;m++) a+=A2[k*576+m*NN+n]*lin[m*36+f*TT+t];
    rg[i]=a;
  }
  __syncthreads();
  for(int i=tid;i<NN*COUT*TT;i+=320){
    int t=i%TT, o=(i/TT)%COUT, n=i/(COUT*TT);
    float a=cheb_bias[o];
    #pragma unroll
    for(int k=0;k<KK;k++)
      #pragma unroll
      for(int f=0;f<FF;f++)
        a += rg[((k*NN+n)*FF+f)*TT+t]*theta[(k*FF+f)*COUT+o];
    xc[i]=fmaxf(a,0.f);
  }
  __syncthreads();
  if(tid<NN*COUT){
    float mu=0;
    for(int t=0;t<TT;t++) mu+=xc[tid*TT+t];
    mu*=(1.f/12.f);
    float var=0;
    for(int t=0;t<TT;t++){ float d=xc[tid*TT+t]-mu; var+=d*d; }
    var*=(1.f/12.f);
    float inv=rsqrtf(var+1e-5f);
    for(int t=0;t<TT;t++) xc[tid*TT+t]=(xc[tid*TT+t]-mu)*inv*ln_g[t]+ln_b[t];
  }
  __syncthreads();
  for(int i=tid;i<NN*COUT;i+=320){
    for(int v=0;v<TT;v++){
      float a=0;
      for(int t=0;t<TT;t++) a+=xc[i*TT+t]*ta_s[t*TT+v];
      xres[i*TT+v]=a;
    }
  }
  for(int i=tid;i<25*TT;i+=320){
    int r=i/TT, t=i%TT;
    float v=(r<NN)? lin[r*36+t*3+0] : lin[t*3+1];
    xres[(288+r)*TT+t]=v;
  }
  __syncthreads();
  for(int i=tid;i<DIN;i+=320){
    for(int t=0;t<TT;t++){
      float a=lib[t];
      #pragma unroll
      for(int u=0;u<TT;u++) a+=xres[i*TT+u]*liw[t*TT+u];
      x_in[((long)b*DIN+i)*TT+t]=a;
    }
  }
}

// ---------- per-(t,b): alpha softmax gate, xi -> bf16 padded [t*32+b][KPI] ----------
__global__ void __launch_bounds__(512) k_alpha(const float* __restrict__ x_in,
    const float* __restrict__ sa2_w, const float* __restrict__ sa2_b,
    unsigned short* __restrict__ xi_b){
  int blk=blockIdx.x; int t=blk>>5, b=blk&31; int tid=threadIdx.x;
  __shared__ float xt[DIN];
  __shared__ float red[512];
  if(tid<DIN) xt[tid]=x_in[((long)b*DIN+tid)*TT+t];
  __syncthreads();
  float z=-1e30f, e=0.f;
  if(tid<DIN){
    float a=sa2_b[tid];
    const float* wr=sa2_w+(long)tid*DIN;
    for(int i=0;i<DIN;i++) a+=xt[i]*wr[i];
    z=sigm(a);
  }
  red[tid]=z; __syncthreads();
  for(int off=256;off>0;off>>=1){ if(tid<off) red[tid]=fmaxf(red[tid],red[tid+off]); __syncthreads(); }
  float mx=red[0]; __syncthreads();
  e=(tid<DIN)?__expf(z-mx):0.f;
  red[tid]=e; __syncthreads();
  for(int off=256;off>0;off>>=1){ if(tid<off) red[tid]+=red[tid+off]; __syncthreads(); }
  float sm=red[0];
  if(tid<KPI){
    unsigned short v=0;
    if(tid<DIN){
      float alpha=e/sm;
      v=f2bf(xt[tid]*alpha+xt[tid]);
    }
    xi_b[(long)blk*KPI+tid]=v;
  }
}

// ---------- Gx[t][b][j] = xi @ W_ih^T + b_ih + b_hh (bf16 MFMA; W_ih fp32 read+cvt in regs) ----------
__global__ void __launch_bounds__(256) k_gx(const unsigned short* __restrict__ xi,
   const float* __restrict__ Wih, const float* __restrict__ b_ih,
   const float* __restrict__ b_hh, float* __restrict__ Gx){
  int w=threadIdx.x>>6, lane=threadIdx.x&63;
  int jt=blockIdx.x*4+w;
  if(jt>=NTILES) return;
  int j0=jt*32;
  int lj=lane&15, lk=lane>>4;
  short8 bfr[10][2];
  #pragma unroll
  for(int ks=0;ks<10;ks++)
    #pragma unroll
    for(int jh=0;jh<2;jh++){
      int j=j0+jh*16+lj;
      short8 bv;
      #pragma unroll
      for(int q=0;q<8;q++){
        int k=ks*32+lk*8+q;
        float f=(j<H4 && k<DIN)? Wih[(long)j*DIN+k] : 0.f;
        bv[q]=(short)f2bf(f);
      }
      bfr[ks][jh]=bv;
    }
  for(int t=0;t<TT;t++){
    f32x4 acc[2][2]={};
    #pragma unroll
    for(int ks=0;ks<10;ks++){
      #pragma unroll
      for(int mh=0;mh<2;mh++){
        short8 a=*(const short8*)(xi + ((long)(t*32+mh*16+lj))*KPI + ks*32 + lk*8);
        acc[mh][0]=mfma16(a,bfr[ks][0],acc[mh][0]);
        acc[mh][1]=mfma16(a,bfr[ks][1],acc[mh][1]);
      }
    }
    #pragma unroll
    for(int mh=0;mh<2;mh++)
      #pragma unroll
      for(int jh=0;jh<2;jh++){
        int j=j0+jh*16+lj;
        if(j<H4){
          float bias=b_ih[j]+b_hh[j];
          #pragma unroll
          for(int r=0;r<4;r++){
            int bb=mh*16+lk*4+r;     // C/D: col=lane&15, row=(lane>>4)*4+r  (m89-verified)
            Gx[((long)t*32+bb)*H4+j]=acc[mh][jh][r]+bias;
          }
        }
      }
  }
}

// ---------- fused LSTM step: gate-aligned j-tile (16 j x 4 gates), MFMA + update epilogue ----------
// Block bi owns j in [bi*16, bi*16+16). Reads hb_r (ping), writes hb_w (pong) + c/hs (block-private).
__global__ void __launch_bounds__(256) k_step(const unsigned short* __restrict__ hb_r,
    unsigned short* __restrict__ hb_w, const unsigned short* __restrict__ Whh,
    const float* __restrict__ Gx, const float* __restrict__ c0,
    float* __restrict__ c, float* __restrict__ hs, int t){
  const int tid=threadIdx.x;
  const int w=tid>>6, lane=tid&63;
  const int j0=blockIdx.x*16;
  const int lj=lane&15, lk=lane>>4;
  const int s0=(118*w)>>2, s1=(118*(w+1))>>2;     // 4-way K split: 29/30/29/30 ksteps
  const int jj=j0+lj;
  long rowb[4];
  #pragma unroll
  for(int g=0;g<4;g++) rowb[g]=(long)min(g*HID+jj, H4-1)*KP;
  f32x4 acc[4][2]={};
  for(int ks=s0;ks<s1;ks++){
    int kofs=ks*32+lk*8;
    short8 a0=*(const short8*)(hb_r + (long)lj*KP + kofs);
    short8 a1=*(const short8*)(hb_r + (long)(16+lj)*KP + kofs);
    #pragma unroll
    for(int g=0;g<4;g++){
      short8 bv=*(const short8*)(Whh + rowb[g] + kofs);
      acc[g][0]=mfma16(a0,bv,acc[g][0]);
      acc[g][1]=mfma16(a1,bv,acc[g][1]);
    }
  }
  __shared__ float red[4][4][512];                 // [wave][gate][bb*16+lj]
  #pragma unroll
  for(int g=0;g<4;g++)
    #pragma unroll
    for(int mh=0;mh<2;mh++)
      #pragma unroll
      for(int r=0;r<4;r++)
        red[w][g][(mh*16+lk*4+r)*16+lj]=acc[g][mh][r];
  __syncthreads();
  for(int p=tid;p<512;p+=256){
    int bb=p>>4, jl=p&15; int j=j0+jl;
    if(j<HID){
      long gxo=((long)t*BSZ+bb)*H4 + j;
      float si=red[0][0][p]+red[1][0][p]+red[2][0][p]+red[3][0][p]+Gx[gxo        ];
      float sf=red[0][1][p]+red[1][1][p]+red[2][1][p]+red[3][1][p]+Gx[gxo+  HID  ];
      float sg=red[0][2][p]+red[1][2][p]+red[2][2][p]+red[3][2][p]+Gx[gxo+2*HID  ];
      float so=red[0][3][p]+red[1][3][p]+red[2][3][p]+red[3][3][p]+Gx[gxo+3*HID  ];
      float gi=sigm(si), gf=sigm(sf), gg=tanhf(sg), go=sigm(so);
      int idx=bb*HID+j;
      float cin=(t==0)?c0[idx]:c[idx];
      float c2=gf*cin+gi*gg;
      float h2=go*tanhf(c2);
      c[idx]=c2;
      hs[(long)t*BSZ*HID+idx]=h2;
      hb_w[(long)bb*KP+j]=f2bf(h2);
    }
  }
}

// ---------- fused tail: beta softmax + weighted output ----------
__global__ void k_tail(const float* __restrict__ hs, const float* __restrict__ ta2_w,
   const float* __restrict__ ta2_b, const float* __restrict__ x_in,
   const float* __restrict__ out_w, const float* __restrict__ out_b,
   float* __restrict__ out0){
  int b=blockIdx.x, tid=threadIdx.x;
  float p[12]={0,0,0,0,0,0,0,0,0,0,0,0};
  for(int idx=tid; idx<TT*HID; idx+=256){
    int t=idx/HID, j=idx-t*HID;
    float v=hs[((long)t*BSZ+b)*HID+j];
    #pragma unroll
    for(int q=0;q<12;q++) p[q]+=v*ta2_w[(long)q*TT*HID+idx];
  }
  __shared__ float red[256];
  __shared__ float bt[12];
  float z[12];
  #pragma unroll
  for(int q=0;q<12;q++){
    __syncthreads();
    red[tid]=p[q]; __syncthreads();
    for(int off=128;off>0;off>>=1){ if(tid<off) red[tid]+=red[tid+off]; __syncthreads(); }
    z[q]=red[0];
  }
  if(tid==0){
    float mx=-1e30f;
    #pragma unroll
    for(int q=0;q<12;q++){ z[q]=fmaxf(z[q]+ta2_b[q],0.f); mx=fmaxf(mx,z[q]); }
    float sm=0;
    #pragma unroll
    for(int q=0;q<12;q++){ z[q]=__expf(z[q]-mx); sm+=z[q]; }
    #pragma unroll
    for(int q=0;q<12;q++) bt[q]=z[q]/sm;
  }
  __syncthreads();
  float acc=0;
  for(int j=tid;j<HID;j+=256){
    float ov=0;
    #pragma unroll
    for(int t=0;t<TT;t++) ov+=hs[((long)t*BSZ+b)*HID+j]*bt[t];
    ov+=x_in[(long)b*HID+j];
    acc+=fmaxf(ov,0.f)*out_w[j];
  }
  __syncthreads();
  red[tid]=acc; __syncthreads();
  for(int off=128;off>0;off>>=1){ if(tid<off) red[tid]+=red[tid+off]; __syncthreads(); }
  if(tid==0) out0[b]=red[0]+out_b[0];
}

extern "C" void kernel_launch(void* const* d_in, const int* in_sizes, int n_in,
                              void* d_out, int out_size, void* d_ws, size_t ws_size,
                              hipStream_t stream){
  (void)in_sizes; (void)n_in; (void)out_size; (void)ws_size;
  const float* X     =(const float*)d_in[0];
  const float* cheb  =(const float*)d_in[1];
  const float* sa_W1 =(const float*)d_in[2];
  const float* sa_W2 =(const float*)d_in[3];
  const float* sa_W3 =(const float*)d_in[4];
  const float* sa_bs =(const float*)d_in[5];
  const float* sa_Vs =(const float*)d_in[6];
  const float* ta_U1 =(const float*)d_in[7];
  const float* ta_U2 =(const float*)d_in[8];
  const float* ta_U3 =(const float*)d_in[9];
  const float* ta_be =(const float*)d_in[10];
  const float* ta_Ve =(const float*)d_in[11];
  const float* theta =(const float*)d_in[12];
  const float* cb    =(const float*)d_in[13];
  const float* ln_g  =(const float*)d_in[14];
  const float* ln_b  =(const float*)d_in[15];
  const float* liw   =(const float*)d_in[16];
  const float* lib   =(const float*)d_in[17];
  const float* sa2_w =(const float*)d_in[18];
  const float* sa2_b =(const float*)d_in[19];
  const float* W_ih  =(const float*)d_in[20];
  const float* W_hh  =(const float*)d_in[21];
  const float* b_ih  =(const float*)d_in[22];
  const float* b_hh  =(const float*)d_in[23];
  const float* ta2_w =(const float*)d_in[24];
  const float* ta2_b =(const float*)d_in[25];
  const float* out_w =(const float*)d_in[26];
  const float* out_b =(const float*)d_in[27];
  const float* h0    =(const float*)d_in[28];
  const float* c0    =(const float*)d_in[29];

  char* w=(char*)d_ws;
  unsigned short* Whh_b=(unsigned short*)(w);                 // 113,461,248
  float* Gx   =(float*)(w+113461248);                         // 23,076,864 -> 136,538,112
  float* hs   =(float*)(w+136538112);                         //  5,769,216 -> 142,307,328
  unsigned short* hb0=(unsigned short*)(w+142307328);         //    241,664 -> 142,548,992
  unsigned short* hb1=(unsigned short*)(w+142548992);         //    241,664 -> 142,790,656
  float* c    =(float*)(w+142790656);                         //    480,768 -> 143,271,424
  float* x_in =(float*)(w+143271424);                         //    480,768 -> 143,752,192
  unsigned short* xi_b=(unsigned short*)(w+143752192);        //    245,760 -> 143,997,952
  float* SA   =(float*)(w+143997952);                         //     73,728
  float* TA   =(float*)(w+144071680);                         //     18,432
  float* s_a  =(float*)(w+144090112);                         //     73,728
  float* t_a  =(float*)(w+144163840);                         //     18,432
  float* out_f=(float*)d_out;                                 // [0..31]=out, [32..]=s_a

  k_convall<<<2048,256,0,stream>>>(W_hh,h0,Whh_b,hb0,hb1);
  k_attn<<<32,256,0,stream>>>(X,sa_W1,sa_W2,sa_W3,sa_bs,sa_Vs,ta_U1,ta_U2,ta_U3,ta_be,ta_Ve,SA,TA);
  k_bsoftmax<<<3,256,0,stream>>>(SA,TA,s_a,t_a,out_f+32);
  k_graph<<<32,320,0,stream>>>(X,cheb,s_a,t_a,theta,cb,ln_g,ln_b,liw,lib,x_in);
  k_alpha<<<384,512,0,stream>>>(x_in,sa2_w,sa2_b,xi_b);
  k_gx<<<118,256,0,stream>>>(xi_b,W_ih,b_ih,b_hh,Gx);
  unsigned short* hb[2]={hb0,hb1};
  for(int t=0;t<TT;t++)
    k_step<<<NB,256,0,stream>>>(hb[t&1],hb[(t+1)&1],Whh_b,Gx,c0,c,hs,t);
  k_tail<<<32,256,0,stream>>>(hs,ta2_w,ta2_b,x_in,out_w,out_b,out_f);
}

// Round 9
// 628.874 us; speedup vs baseline: 7.5481x; 1.0069x over previous
//
#include <hip/hip_runtime.h>

#define BSZ 32
#define NN 24
#define TT 12
#define FF 3
#define KK 3
#define COUT 12
#define DIN 313          // N*COUT + N + 1
#define HID 3756         // DIN*T
#define H4 15024         // 4*HID
#define KP 3776          // HID padded to 118*32
#define KPI 320          // DIN padded to 10*32
#define NTILES 470       // ceil(15024/32)
#define NB 235           // ceil(3756/16) j-tiles for fused step

using short8 = __attribute__((ext_vector_type(8))) short;
using f32x4  = __attribute__((ext_vector_type(4))) float;

__device__ inline unsigned short f2bf(float f){
  union{float f; unsigned u;} v; v.f=f;
  unsigned u=v.u;
  return (unsigned short)((u + 0x7FFFu + ((u>>16)&1u))>>16);
}
__device__ inline f32x4 mfma16(short8 a, short8 b, f32x4 c){
  return __builtin_amdgcn_mfma_f32_16x16x32_bf16(a,b,c,0,0,0);
}
__device__ inline float sigm(float x){ return 1.f/(1.f+expf(-x)); }

// ---------- fused fp32->bf16 conversion: W_hh rows + h0 rows (dual-dest) ----------
__global__ void k_convall(const float* __restrict__ W, const float* __restrict__ h0f,
    unsigned short* __restrict__ Wb, unsigned short* __restrict__ hb0,
    unsigned short* __restrict__ hb1){
  const int g4 = KP>>2;                 // 944 groups of 4
  long total = (long)(H4+BSZ)*g4;
  for(long i=(long)blockIdx.x*blockDim.x+threadIdx.x; i<total; i+=(long)gridDim.x*blockDim.x){
    int g=(int)(i%g4); int r=(int)(i/g4);
    int k=g*4;
    const float* src;
    bool isW = r<H4;
    src = isW ? (W + (long)r*HID) : (h0f + (long)(r-H4)*HID);
    ushort4 o;
    if(k+3<HID){
      float4 v=*(const float4*)(src+k);
      o.x=f2bf(v.x); o.y=f2bf(v.y); o.z=f2bf(v.z); o.w=f2bf(v.w);
    } else {
      float vv[4];
      #pragma unroll
      for(int q=0;q<4;q++){ int kk=k+q; vv[q]=(kk<HID)? src[kk] : 0.f; }
      o.x=f2bf(vv[0]); o.y=f2bf(vv[1]); o.z=f2bf(vv[2]); o.w=f2bf(vv[3]);
    }
    if(isW) *(ushort4*)(Wb + (long)r*KP + k) = o;
    else {
      *(ushort4*)(hb0 + (long)(r-H4)*KP + k) = o;
      *(ushort4*)(hb1 + (long)(r-H4)*KP + k) = o;   // init pad (and values) of pong buffer
    }
  }
}

// ---------- spatial + temporal attention (pre batch-softmax), per batch ----------
__global__ void k_attn(const float* __restrict__ X, const float* __restrict__ sa_W1,
   const float* __restrict__ sa_W2, const float* __restrict__ sa_W3,
   const float* __restrict__ sa_bs, const float* __restrict__ sa_Vs,
   const float* __restrict__ ta_U1, const float* __restrict__ ta_U2,
   const float* __restrict__ ta_U3, const float* __restrict__ ta_be,
   const float* __restrict__ ta_Ve,
   float* __restrict__ SA_pre, float* __restrict__ TA_pre){
  int b=blockIdx.x, tid=threadIdx.x;
  __shared__ float lin[864];            // raw X[b], layout [n][t][f]
  __shared__ float lhs[NN*TT];
  __shared__ float rhs[TT*NN];
  __shared__ float P[NN*NN];
  __shared__ float S[NN*NN];
  __shared__ float lhsT[TT*NN];
  __shared__ float rhsT[NN*TT];
  __shared__ float PT[TT*TT];
  __shared__ float E[TT*TT];
  for(int i=tid;i<864;i+=256) lin[i]=X[b*864+i];
  __syncthreads();
  for(int i=tid;i<NN*TT;i+=256){ int n=i/TT, t=i%TT;
    float acc=0;
    #pragma unroll
    for(int f=0;f<FF;f++){
      float t1=0;
      for(int u=0;u<TT;u++) t1 += lin[n*36+u*3+f]*sa_W1[u];
      acc += t1*sa_W2[f*TT+t];
    }
    lhs[n*TT+t]=acc;
    float r=0;
    #pragma unroll
    for(int f=0;f<FF;f++) r += sa_W3[f]*lin[n*36+t*3+f];
    rhs[t*NN+n]=r;
  }
  for(int i=tid;i<TT*NN;i+=256){ int t=i/NN, n=i%NN;
    float acc=0;
    #pragma unroll
    for(int f=0;f<FF;f++){
      float t1=0;
      for(int m=0;m<NN;m++) t1 += lin[m*36+t*3+f]*ta_U1[m];
      acc += t1*ta_U2[f*NN+n];
    }
    lhsT[t*NN+n]=acc;
    float r=0;
    #pragma unroll
    for(int f=0;f<FF;f++) r += ta_U3[f]*lin[n*36+t*3+f];
    rhsT[n*TT+t]=r;
  }
  __syncthreads();
  for(int i=tid;i<NN*NN;i+=256){ int n=i/NN,m=i%NN;
    float a=0;
    for(int t=0;t<TT;t++) a+=lhs[n*TT+t]*rhs[t*NN+m];
    P[i]=sigm(a+sa_bs[i]);
  }
  for(int i=tid;i<TT*TT;i+=256){ int t=i/TT,u=i%TT;
    float a=0;
    for(int n=0;n<NN;n++) a+=lhsT[t*NN+n]*rhsT[n*TT+u];
    PT[i]=sigm(a+ta_be[i]);
  }
  __syncthreads();
  for(int i=tid;i<NN*NN;i+=256){ int n=i/NN,k=i%NN;
    float a=0;
    for(int m=0;m<NN;m++) a+=sa_Vs[n*NN+m]*P[m*NN+k];
    S[i]=a;
  }
  for(int i=tid;i<TT*TT;i+=256){ int t=i/TT,v=i%TT;
    float a=0;
    for(int u=0;u<TT;u++) a+=ta_Ve[t*TT+u]*PT[u*TT+v];
    E[i]=a;
  }
  __syncthreads();
  if(tid<NN){ int k=tid;
    float mx=-1e30f;
    for(int n=0;n<NN;n++) mx=fmaxf(mx,S[n*NN+k]);
    float sm=0;
    for(int n=0;n<NN;n++) sm+=__expf(S[n*NN+k]-mx);
    for(int n=0;n<NN;n++){
      float v=__expf(S[n*NN+k]-mx)/sm;
      SA_pre[b*576+n*NN+k]=sigm(v);
    }
  }
  if(tid>=32 && tid<32+TT){ int v=tid-32;
    float mx=-1e30f;
    for(int t=0;t<TT;t++) mx=fmaxf(mx,E[t*TT+v]);
    float sm=0;
    for(int t=0;t<TT;t++) sm+=__expf(E[t*TT+v]-mx);
    for(int t=0;t<TT;t++){
      float e=__expf(E[t*TT+v]-mx)/sm;
      TA_pre[b*144+t*TT+v]=sigm(e);
    }
  }
}

// ---------- softmax over batch axis; s_a also written to OUTPUT as float ----------
__global__ void k_bsoftmax(const float* __restrict__ SA_pre, const float* __restrict__ TA_pre,
    float* __restrict__ s_a, float* __restrict__ t_a, float* __restrict__ out_sa){
  int i=blockIdx.x*blockDim.x+threadIdx.x;
  if(i<576){
    float mx=-1e30f;
    for(int b=0;b<BSZ;b++) mx=fmaxf(mx,SA_pre[b*576+i]);
    float sm=0;
    for(int b=0;b<BSZ;b++) sm+=__expf(SA_pre[b*576+i]-mx);
    for(int b=0;b<BSZ;b++){
      float v=__expf(SA_pre[b*576+i]-mx)/sm;
      s_a[b*576+i]=v;
      out_sa[b*576+i]=v;
    }
  } else if(i<720){
    int j=i-576;
    float mx=-1e30f;
    for(int b=0;b<BSZ;b++) mx=fmaxf(mx,TA_pre[b*144+j]);
    float sm=0;
    for(int b=0;b<BSZ;b++) sm+=__expf(TA_pre[b*144+j]-mx);
    for(int b=0;b<BSZ;b++) t_a[b*144+j]=__expf(TA_pre[b*144+j]-mx)/sm;
  }
}

// ---------- graph conv + LN + temporal mix + input layer, per batch ----------
__global__ void k_graph(const float* __restrict__ X, const float* __restrict__ cheb,
  const float* __restrict__ s_a, const float* __restrict__ t_a,
  const float* __restrict__ theta, const float* __restrict__ cheb_bias,
  const float* __restrict__ ln_g, const float* __restrict__ ln_b,
  const float* __restrict__ liw, const float* __restrict__ lib,
  float* __restrict__ x_in){
  int b=blockIdx.x, tid=threadIdx.x;
  __shared__ float lin[864];
  __shared__ float A2[KK*NN*NN];
  __shared__ float rg[KK*NN*FF*TT];
  __shared__ float xc[NN*COUT*TT];
  __shared__ float xres[DIN*TT];
  __shared__ float ta_s[TT*TT];
  for(int i=tid;i<864;i+=320) lin[i]=X[b*864+i];
  for(int i=tid;i<KK*NN*NN;i+=320){ int mn=i%576; A2[i]=cheb[i]*s_a[b*576+mn]; }
  for(int i=tid;i<144;i+=320) ta_s[i]=t_a[b*144+i];
  __syncthreads();
  for(int i=tid;i<KK*NN*FF*TT;i+=320){
    int t=i%TT, f=(i/TT)%FF, n=(i/36)%NN, k=i/864;
    float a=0;
    for(int m=0;m<NN;m++) a+=A2[k*576+m*NN+n]*lin[m*36+f*TT+t];
    rg[i]=a;
  }
  __syncthreads();
  for(int i=tid;i<NN*COUT*TT;i+=320){
    int t=i%TT, o=(i/TT)%COUT, n=i/(COUT*TT);
    float a=cheb_bias[o];
    #pragma unroll
    for(int k=0;k<KK;k++)
      #pragma unroll
      for(int f=0;f<FF;f++)
        a += rg[((k*NN+n)*FF+f)*TT+t]*theta[(k*FF+f)*COUT+o];
    xc[i]=fmaxf(a,0.f);
  }
  __syncthreads();
  if(tid<NN*COUT){
    float mu=0;
    for(int t=0;t<TT;t++) mu+=xc[tid*TT+t];
    mu*=(1.f/12.f);
    float var=0;
    for(int t=0;t<TT;t++){ float d=xc[tid*TT+t]-mu; var+=d*d; }
    var*=(1.f/12.f);
    float inv=rsqrtf(var+1e-5f);
    for(int t=0;t<TT;t++) xc[tid*TT+t]=(xc[tid*TT+t]-mu)*inv*ln_g[t]+ln_b[t];
  }
  __syncthreads();
  for(int i=tid;i<NN*COUT;i+=320){
    for(int v=0;v<TT;v++){
      float a=0;
      for(int t=0;t<TT;t++) a+=xc[i*TT+t]*ta_s[t*TT+v];
      xres[i*TT+v]=a;
    }
  }
  for(int i=tid;i<25*TT;i+=320){
    int r=i/TT, t=i%TT;
    float v=(r<NN)? lin[r*36+t*3+0] : lin[t*3+1];
    xres[(288+r)*TT+t]=v;
  }
  __syncthreads();
  for(int i=tid;i<DIN;i+=320){
    for(int t=0;t<TT;t++){
      float a=lib[t];
      #pragma unroll
      for(int u=0;u<TT;u++) a+=xres[i*TT+u]*liw[t*TT+u];
      x_in[((long)b*DIN+i)*TT+t]=a;
    }
  }
}

// ---------- per-(t,b): alpha softmax gate, xi -> bf16 padded [t*32+b][KPI] ----------
__global__ void __launch_bounds__(512) k_alpha(const float* __restrict__ x_in,
    const float* __restrict__ sa2_w, const float* __restrict__ sa2_b,
    unsigned short* __restrict__ xi_b){
  int blk=blockIdx.x; int t=blk>>5, b=blk&31; int tid=threadIdx.x;
  __shared__ float xt[DIN];
  __shared__ float red[512];
  if(tid<DIN) xt[tid]=x_in[((long)b*DIN+tid)*TT+t];
  __syncthreads();
  float z=-1e30f, e=0.f;
  if(tid<DIN){
    float a=sa2_b[tid];
    const float* wr=sa2_w+(long)tid*DIN;
    for(int i=0;i<DIN;i++) a+=xt[i]*wr[i];
    z=sigm(a);
  }
  red[tid]=z; __syncthreads();
  for(int off=256;off>0;off>>=1){ if(tid<off) red[tid]=fmaxf(red[tid],red[tid+off]); __syncthreads(); }
  float mx=red[0]; __syncthreads();
  e=(tid<DIN)?__expf(z-mx):0.f;
  red[tid]=e; __syncthreads();
  for(int off=256;off>0;off>>=1){ if(tid<off) red[tid]+=red[tid+off]; __syncthreads(); }
  float sm=red[0];
  if(tid<KPI){
    unsigned short v=0;
    if(tid<DIN){
      float alpha=e/sm;
      v=f2bf(xt[tid]*alpha+xt[tid]);
    }
    xi_b[(long)blk*KPI+tid]=v;
  }
}

// ---------- Gx[t][b][j] = xi @ W_ih^T + b_ih + b_hh (bf16 MFMA; W_ih fp32 read+cvt in regs) ----------
__global__ void __launch_bounds__(256) k_gx(const unsigned short* __restrict__ xi,
   const float* __restrict__ Wih, const float* __restrict__ b_ih,
   const float* __restrict__ b_hh, float* __restrict__ Gx){
  int w=threadIdx.x>>6, lane=threadIdx.x&63;
  int jt=blockIdx.x*4+w;
  if(jt>=NTILES) return;
  int j0=jt*32;
  int lj=lane&15, lk=lane>>4;
  short8 bfr[10][2];
  #pragma unroll
  for(int ks=0;ks<10;ks++)
    #pragma unroll
    for(int jh=0;jh<2;jh++){
      int j=j0+jh*16+lj;
      short8 bv;
      #pragma unroll
      for(int q=0;q<8;q++){
        int k=ks*32+lk*8+q;
        float f=(j<H4 && k<DIN)? Wih[(long)j*DIN+k] : 0.f;
        bv[q]=(short)f2bf(f);
      }
      bfr[ks][jh]=bv;
    }
  for(int t=0;t<TT;t++){
    f32x4 acc[2][2]={};
    #pragma unroll
    for(int ks=0;ks<10;ks++){
      #pragma unroll
      for(int mh=0;mh<2;mh++){
        short8 a=*(const short8*)(xi + ((long)(t*32+mh*16+lj))*KPI + ks*32 + lk*8);
        acc[mh][0]=mfma16(a,bfr[ks][0],acc[mh][0]);
        acc[mh][1]=mfma16(a,bfr[ks][1],acc[mh][1]);
      }
    }
    #pragma unroll
    for(int mh=0;mh<2;mh++)
      #pragma unroll
      for(int jh=0;jh<2;jh++){
        int j=j0+jh*16+lj;
        if(j<H4){
          float bias=b_ih[j]+b_hh[j];
          #pragma unroll
          for(int r=0;r<4;r++){
            int bb=mh*16+lk*4+r;     // C/D: col=lane&15, row=(lane>>4)*4+r  (m89-verified)
            Gx[((long)t*32+bb)*H4+j]=acc[mh][jh][r]+bias;
          }
        }
      }
  }
}

// ---------- fused LSTM step: gate-aligned j-tile, 8-wave K-split (TLP x2), MFMA + update epilogue ----------
// Block bi owns j in [bi*16, bi*16+16). Reads hb_r (ping), writes hb_w (pong) + c/hs (block-private).
__global__ void __launch_bounds__(512) k_step(const unsigned short* __restrict__ hb_r,
    unsigned short* __restrict__ hb_w, const unsigned short* __restrict__ Whh,
    const float* __restrict__ Gx, const float* __restrict__ c0,
    float* __restrict__ c, float* __restrict__ hs, int t){
  const int tid=threadIdx.x;
  const int w=tid>>6, lane=tid&63;               // 8 waves
  const int j0=blockIdx.x*16;
  const int lj=lane&15, lk=lane>>4;
  const int s0=(118*w)>>3, s1=(118*(w+1))>>3;    // 8-way K split: 14-15 ksteps each
  const int jj=j0+lj;
  long rowb[4];
  #pragma unroll
  for(int g=0;g<4;g++) rowb[g]=(long)min(g*HID+jj, H4-1)*KP;
  f32x4 acc[4][2]={};
  #pragma unroll 2
  for(int ks=s0;ks<s1;ks++){
    int kofs=ks*32+lk*8;
    short8 a0=*(const short8*)(hb_r + (long)lj*KP + kofs);
    short8 a1=*(const short8*)(hb_r + (long)(16+lj)*KP + kofs);
    #pragma unroll
    for(int g=0;g<4;g++){
      short8 bv=*(const short8*)(Whh + rowb[g] + kofs);
      acc[g][0]=mfma16(a0,bv,acc[g][0]);
      acc[g][1]=mfma16(a1,bv,acc[g][1]);
    }
  }
  __shared__ float red[8][4][512];                // [wave][gate][bb*16+lj] = 64 KB
  #pragma unroll
  for(int g=0;g<4;g++)
    #pragma unroll
    for(int mh=0;mh<2;mh++)
      #pragma unroll
      for(int r=0;r<4;r++)
        red[w][g][(mh*16+lk*4+r)*16+lj]=acc[g][mh][r];
  __syncthreads();
  if(tid<512){
    int p=tid;
    int bb=p>>4, jl=p&15; int j=j0+jl;
    if(j<HID){
      long gxo=((long)t*BSZ+bb)*H4 + j;
      float si=0,sf=0,sg=0,so=0;
      #pragma unroll
      for(int ww=0;ww<8;ww++){
        si+=red[ww][0][p]; sf+=red[ww][1][p];
        sg+=red[ww][2][p]; so+=red[ww][3][p];
      }
      si+=Gx[gxo]; sf+=Gx[gxo+HID]; sg+=Gx[gxo+2*HID]; so+=Gx[gxo+3*HID];
      float gi=sigm(si), gf=sigm(sf), gg=tanhf(sg), go=sigm(so);
      int idx=bb*HID+j;
      float cin=(t==0)?c0[idx]:c[idx];
      float c2=gf*cin+gi*gg;
      float h2=go*tanhf(c2);
      c[idx]=c2;
      hs[(long)t*BSZ*HID+idx]=h2;
      hb_w[(long)bb*KP+j]=f2bf(h2);
    }
  }
}

// ---------- fused tail: beta softmax + weighted output ----------
__global__ void k_tail(const float* __restrict__ hs, const float* __restrict__ ta2_w,
   const float* __restrict__ ta2_b, const float* __restrict__ x_in,
   const float* __restrict__ out_w, const float* __restrict__ out_b,
   float* __restrict__ out0){
  int b=blockIdx.x, tid=threadIdx.x;
  float p[12]={0,0,0,0,0,0,0,0,0,0,0,0};
  for(int idx=tid; idx<TT*HID; idx+=256){
    int t=idx/HID, j=idx-t*HID;
    float v=hs[((long)t*BSZ+b)*HID+j];
    #pragma unroll
    for(int q=0;q<12;q++) p[q]+=v*ta2_w[(long)q*TT*HID+idx];
  }
  __shared__ float red[256];
  __shared__ float bt[12];
  float z[12];
  #pragma unroll
  for(int q=0;q<12;q++){
    __syncthreads();
    red[tid]=p[q]; __syncthreads();
    for(int off=128;off>0;off>>=1){ if(tid<off) red[tid]+=red[tid+off]; __syncthreads(); }
    z[q]=red[0];
  }
  if(tid==0){
    float mx=-1e30f;
    #pragma unroll
    for(int q=0;q<12;q++){ z[q]=fmaxf(z[q]+ta2_b[q],0.f); mx=fmaxf(mx,z[q]); }
    float sm=0;
    #pragma unroll
    for(int q=0;q<12;q++){ z[q]=__expf(z[q]-mx); sm+=z[q]; }
    #pragma unroll
    for(int q=0;q<12;q++) bt[q]=z[q]/sm;
  }
  __syncthreads();
  float acc=0;
  for(int j=tid;j<HID;j+=256){
    float ov=0;
    #pragma unroll
    for(int t=0;t<TT;t++) ov+=hs[((long)t*BSZ+b)*HID+j]*bt[t];
    ov+=x_in[(long)b*HID+j];
    acc+=fmaxf(ov,0.f)*out_w[j];
  }
  __syncthreads();
  red[tid]=acc; __syncthreads();
  for(int off=128;off>0;off>>=1){ if(tid<off) red[tid]+=red[tid+off]; __syncthreads(); }
  if(tid==0) out0[b]=red[0]+out_b[0];
}

extern "C" void kernel_launch(void* const* d_in, const int* in_sizes, int n_in,
                              void* d_out, int out_size, void* d_ws, size_t ws_size,
                              hipStream_t stream){
  (void)in_sizes; (void)n_in; (void)out_size; (void)ws_size;
  const float* X     =(const float*)d_in[0];
  const float* cheb  =(const float*)d_in[1];
  const float* sa_W1 =(const float*)d_in[2];
  const float* sa_W2 =(const float*)d_in[3];
  const float* sa_W3 =(const float*)d_in[4];
  const float* sa_bs =(const float*)d_in[5];
  const float* sa_Vs =(const float*)d_in[6];
  const float* ta_U1 =(const float*)d_in[7];
  const float* ta_U2 =(const float*)d_in[8];
  const float* ta_U3 =(const float*)d_in[9];
  const float* ta_be =(const float*)d_in[10];
  const float* ta_Ve =(const float*)d_in[11];
  const float* theta =(const float*)d_in[12];
  const float* cb    =(const float*)d_in[13];
  const float* ln_g  =(const float*)d_in[14];
  const float* ln_b  =(const float*)d_in[15];
  const float* liw   =(const float*)d_in[16];
  const float* lib   =(const float*)d_in[17];
  const float* sa2_w =(const float*)d_in[18];
  const float* sa2_b =(const float*)d_in[19];
  const float* W_ih  =(const float*)d_in[20];
  const float* W_hh  =(const float*)d_in[21];
  const float* b_ih  =(const float*)d_in[22];
  const float* b_hh  =(const float*)d_in[23];
  const float* ta2_w =(const float*)d_in[24];
  const float* ta2_b =(const float*)d_in[25];
  const float* out_w =(const float*)d_in[26];
  const float* out_b =(const float*)d_in[27];
  const float* h0    =(const float*)d_in[28];
  const float* c0    =(const float*)d_in[29];

  char* w=(char*)d_ws;
  unsigned short* Whh_b=(unsigned short*)(w);                 // 113,461,248
  float* Gx   =(float*)(w+113461248);                         // 23,076,864 -> 136,538,112
  float* hs   =(float*)(w+136538112);                         //  5,769,216 -> 142,307,328
  unsigned short* hb0=(unsigned short*)(w+142307328);         //    241,664 -> 142,548,992
  unsigned short* hb1=(unsigned short*)(w+142548992);         //    241,664 -> 142,790,656
  float* c    =(float*)(w+142790656);                         //    480,768 -> 143,271,424
  float* x_in =(float*)(w+143271424);                         //    480,768 -> 143,752,192
  unsigned short* xi_b=(unsigned short*)(w+143752192);        //    245,760 -> 143,997,952
  float* SA   =(float*)(w+143997952);                         //     73,728
  float* TA   =(float*)(w+144071680);                         //     18,432
  float* s_a  =(float*)(w+144090112);                         //     73,728
  float* t_a  =(float*)(w+144163840);                         //     18,432
  float* out_f=(float*)d_out;                                 // [0..31]=out, [32..]=s_a

  k_convall<<<2048,256,0,stream>>>(W_hh,h0,Whh_b,hb0,hb1);
  k_attn<<<32,256,0,stream>>>(X,sa_W1,sa_W2,sa_W3,sa_bs,sa_Vs,ta_U1,ta_U2,ta_U3,ta_be,ta_Ve,SA,TA);
  k_bsoftmax<<<3,256,0,stream>>>(SA,TA,s_a,t_a,out_f+32);
  k_graph<<<32,320,0,stream>>>(X,cheb,s_a,t_a,theta,cb,ln_g,ln_b,liw,lib,x_in);
  k_alpha<<<384,512,0,stream>>>(x_in,sa2_w,sa2_b,xi_b);
  k_gx<<<118,256,0,stream>>>(xi_b,W_ih,b_ih,b_hh,Gx);
  unsigned short* hb[2]={hb0,hb1};
  for(int t=0;t<TT;t++)
    k_step<<<NB,512,0,stream>>>(hb[t&1],hb[(t+1)&1],Whh_b,Gx,c0,c,hs,t);
  k_tail<<<32,256,0,stream>>>(hs,ta2_w,ta2_b,x_in,out_w,out_b,out_f);
}